// Round 1
// baseline (638.761 us; speedup 1.0000x reference)
//
#include <hip/hip_runtime.h>

#define BB 4
#define NN 512
#define NH 256
#define DD 64

__device__ __forceinline__ float wred_sum(float v) {
  v += __shfl_xor(v, 32);
  v += __shfl_xor(v, 16);
  v += __shfl_xor(v, 8);
  v += __shfl_xor(v, 4);
  v += __shfl_xor(v, 2);
  v += __shfl_xor(v, 1);
  return v;
}

__device__ __forceinline__ float wred_max(float v) {
  v = fmaxf(v, __shfl_xor(v, 32));
  v = fmaxf(v, __shfl_xor(v, 16));
  v = fmaxf(v, __shfl_xor(v, 8));
  v = fmaxf(v, __shfl_xor(v, 4));
  v = fmaxf(v, __shfl_xor(v, 2));
  v = fmaxf(v, __shfl_xor(v, 1));
  return v;
}

// tanh(t) = 1 - 2/(exp(2t)+1); v_exp + v_rcp, ~8 instrs, abs err ~1e-7
__device__ __forceinline__ float fast_tanh(float t) {
  t = fminf(15.f, fmaxf(-15.f, t));
  float z = __expf(2.f * t);
  return 1.f - 2.f * __builtin_amdgcn_rcpf(z + 1.f);
}

// K1: x[b,n,:] = (n<256 ? x1@W_t1+b_t1 : x2@W_t2+b_t2)
__global__ __launch_bounds__(256)
void k1_build_x(const float* __restrict__ x1, const float* __restrict__ x2,
                const float* __restrict__ W_t1, const float* __restrict__ b_t1,
                const float* __restrict__ W_t2, const float* __restrict__ b_t2,
                float* __restrict__ X) {
  const int tid = threadIdx.x;
  const int lane = tid & 63;
  const int rq = tid >> 6;
  const int r = blockIdx.x * 4 + rq;   // 0..2047
  const int b = r >> 9;
  const int n = r & 511;
  const float* src; const float* W; const float* bias;
  if (n < NH) { src = x1 + (b * NH + n) * DD;        W = W_t1; bias = b_t1; }
  else        { src = x2 + (b * NH + (n - NH)) * DD; W = W_t2; bias = b_t2; }
  const float4* s4 = reinterpret_cast<const float4*>(src);
  float t0 = 0.f, t1 = 0.f, t2 = 0.f, t3 = 0.f;
#pragma unroll
  for (int c = 0; c < 16; ++c) {
    const float4 v = s4[c];
    t0 = fmaf(v.x, W[(4 * c + 0) * DD + lane], t0);
    t1 = fmaf(v.y, W[(4 * c + 1) * DD + lane], t1);
    t2 = fmaf(v.z, W[(4 * c + 2) * DD + lane], t2);
    t3 = fmaf(v.w, W[(4 * c + 3) * DD + lane], t3);
  }
  X[r * DD + lane] = ((t0 + t1) + (t2 + t3)) + bias[lane];
}

// K2: master[b,:] = mean_n x[b,n,:]
__global__ __launch_bounds__(256)
void k2_master_mean(const float* __restrict__ X, float* __restrict__ master) {
  const int b = blockIdx.x;
  const int tid = threadIdx.x;
  const int lane = tid & 63;
  const int q = tid >> 6;
  __shared__ float red[4][DD];
  float s = 0.f;
  for (int n = q; n < NN; n += 4)
    s += X[(b * NN + n) * DD + lane];
  red[q][lane] = s;
  __syncthreads();
  if (q == 0) {
    master[b * DD + lane] =
        (red[0][lane] + red[1][lane] + red[2][lane] + red[3][lane]) * (1.f / 512.f);
  }
}

// K3: fused scores -> softmax_j -> agg = att @ x.  Block: (b, 4 rows i), 512 thr.
// Lane owns channel o; wave w owns j-chunk [64w, 64w+64).
__global__ __launch_bounds__(512, 2)
void k3_att_agg(const float* __restrict__ X,
                const float* __restrict__ W_att,
                const float* __restrict__ b_att,
                const float* __restrict__ w11,
                const float* __restrict__ w22,
                const float* __restrict__ w12,
                float* __restrict__ agg) {
  const int b = blockIdx.y;
  const int i0 = blockIdx.x * 4;
  const int tid = threadIdx.x;
  const int lane = tid & 63;
  const int w = tid >> 6;        // 0..7
  const int jbase = w << 6;

  __shared__ float sc[4][NN];    // scores, then att
  __shared__ float red[8][DD];
  __shared__ float reds[8];

  const float* __restrict__ Xb = X + b * NN * DD;
  const float bl = b_att[lane];

  // ---- phase 1: scores[i][j] = w_sel . tanh(diag(x_i) W_att^T x_j + b) ----
  for (int i = 0; i < 4; ++i) {
    const int irow = i0 + i;
    const float* xi = Xb + irow * DD;
    float mc[DD];
#pragma unroll
    for (int d = 0; d < DD; ++d)
      mc[d] = xi[d] * W_att[d * DD + lane];
    const float* wsel = (irow < NH) ? ((w < 4) ? w11 : w12)
                                    : ((w < 4) ? w12 : w22);
    const float wl = wsel[lane];
    float sc_mine = 0.f;
    for (int jj = 0; jj < 64; ++jj) {
      const float4* xj4 =
          reinterpret_cast<const float4*>(Xb + (jbase + jj) * DD);
      float t0 = 0.f, t1 = 0.f, t2 = 0.f, t3 = 0.f;
#pragma unroll
      for (int c = 0; c < 16; ++c) {
        const float4 v = xj4[c];   // wave-uniform broadcast load
        t0 = fmaf(v.x, mc[4 * c + 0], t0);
        t1 = fmaf(v.y, mc[4 * c + 1], t1);
        t2 = fmaf(v.z, mc[4 * c + 2], t2);
        t3 = fmaf(v.w, mc[4 * c + 3], t3);
      }
      const float e = fast_tanh(((t0 + t1) + (t2 + t3)) + bl);
      const float s = wred_sum(e * wl);
      if (lane == jj) sc_mine = s;   // lane l ends holding score j=jbase+l
    }
    sc[i][jbase + lane] = sc_mine;
  }
  __syncthreads();

  // ---- phase 2: softmax over j (512) + agg row ----
  for (int i = 0; i < 4; ++i) {
    const float v = sc[i][tid];
    float wm = wred_max(v);
    if (lane == 0) reds[w] = wm;
    __syncthreads();
    float bm = reds[0];
#pragma unroll
    for (int k = 1; k < 8; ++k) bm = fmaxf(bm, reds[k]);
    const float e = __expf(v - bm);
    float wsm = wred_sum(e);
    __syncthreads();
    if (lane == 0) reds[w] = wsm;
    __syncthreads();
    float bs = reds[0];
#pragma unroll
    for (int k = 1; k < 8; ++k) bs += reds[k];
    sc[i][tid] = e * (1.f / bs);
    __syncthreads();

    float acc = 0.f;
    for (int jj = 0; jj < 64; ++jj)
      acc = fmaf(sc[i][jbase + jj], Xb[(jbase + jj) * DD + lane], acc);
    red[w][lane] = acc;
    __syncthreads();
    if (w == 0) {
      float s = 0.f;
#pragma unroll
      for (int k = 0; k < 8; ++k) s += red[k][lane];
      agg[(b * NN + i0 + i) * DD + lane] = s;
    }
    __syncthreads();
  }
}

// K3b: logits[b,i] = wM . tanh((x_i * master) @ W_attM + b_attM)
__global__ __launch_bounds__(64)
void k3b_mlogit(const float* __restrict__ X, const float* __restrict__ master,
                const float* __restrict__ W_attM, const float* __restrict__ b_attM,
                const float* __restrict__ wM, float* __restrict__ logits) {
  const int b = blockIdx.y;
  const int lane = threadIdx.x;
  const float bl = b_attM[lane];
  const float wl = wM[lane];
  const float4* m4 = reinterpret_cast<const float4*>(master + b * DD);
  for (int k = 0; k < 8; ++k) {
    const int i = blockIdx.x * 8 + k;
    const float4* xi4 = reinterpret_cast<const float4*>(X + (b * NN + i) * DD);
    float t0 = 0.f, t1 = 0.f, t2 = 0.f, t3 = 0.f;
#pragma unroll
    for (int c = 0; c < 16; ++c) {
      const float4 xv = xi4[c];
      const float4 mv = m4[c];
      t0 = fmaf(xv.x * mv.x, W_attM[(4 * c + 0) * DD + lane], t0);
      t1 = fmaf(xv.y * mv.y, W_attM[(4 * c + 1) * DD + lane], t1);
      t2 = fmaf(xv.z * mv.z, W_attM[(4 * c + 2) * DD + lane], t2);
      t3 = fmaf(xv.w * mv.w, W_attM[(4 * c + 3) * DD + lane], t3);
    }
    const float e = fast_tanh(((t0 + t1) + (t2 + t3)) + bl);
    const float s = wred_sum(e * wl);
    if (lane == 0) logits[b * NN + i] = s;
  }
}

// K4: softmax_n(logits) -> agg_m -> master_new (written to tail of out)
__global__ __launch_bounds__(256)
void k4_master_new(const float* __restrict__ X, const float* __restrict__ master,
                   const float* __restrict__ logits,
                   const float* __restrict__ W_paM, const float* __restrict__ b_paM,
                   const float* __restrict__ W_poM, const float* __restrict__ b_poM,
                   float* __restrict__ out) {
  const int b = blockIdx.x;
  const int tid = threadIdx.x;
  const int lane = tid & 63;
  const int q = tid >> 6;
  __shared__ float red[4][DD];
  __shared__ float r4[4];
  __shared__ float aggm_s[DD];
  __shared__ float mrow_s[DD];
  const float* lg = logits + b * NN;
  const float v0 = lg[tid];
  const float v1 = lg[tid + 256];
  float mx = wred_max(fmaxf(v0, v1));
  if (lane == 0) r4[q] = mx;
  __syncthreads();
  mx = fmaxf(fmaxf(r4[0], r4[1]), fmaxf(r4[2], r4[3]));
  float es = __expf(v0 - mx) + __expf(v1 - mx);
  es = wred_sum(es);
  __syncthreads();
  if (lane == 0) r4[q] = es;
  __syncthreads();
  const float S = r4[0] + r4[1] + r4[2] + r4[3];
  const float invS = 1.f / S;

  float acc = 0.f;
  for (int nn = q * 128; nn < q * 128 + 128; ++nn) {
    const float a = __expf(lg[nn] - mx);
    acc = fmaf(a, X[(b * NN + nn) * DD + lane], acc);
  }
  red[q][lane] = acc;
  __syncthreads();
  if (q == 0) {
    aggm_s[lane] =
        (red[0][lane] + red[1][lane] + red[2][lane] + red[3][lane]) * invS;
    mrow_s[lane] = master[b * DD + lane];
  }
  __syncthreads();
  float p = 0.f;
  for (int d = q * 16; d < q * 16 + 16; ++d) {
    p = fmaf(aggm_s[d], W_paM[d * DD + lane], p);
    p = fmaf(mrow_s[d], W_poM[d * DD + lane], p);
  }
  __syncthreads();
  red[q][lane] = p;
  __syncthreads();
  if (q == 0) {
    out[2 * BB * NH * DD + b * DD + lane] =
        red[0][lane] + red[1][lane] + red[2][lane] + red[3][lane] +
        b_paM[lane] + b_poM[lane];
  }
}

// K5: y = selu(BN(agg@W_pa + x@W_po + biases)), split-written to out
__global__ __launch_bounds__(256)
void k5_y(const float* __restrict__ X, const float* __restrict__ agg,
          const float* __restrict__ W_pa, const float* __restrict__ b_pa,
          const float* __restrict__ W_po, const float* __restrict__ b_po,
          const float* __restrict__ gamma, const float* __restrict__ beta,
          float* __restrict__ out) {
  const int tid = threadIdx.x;
  const int lane = tid & 63;
  const int rq = tid >> 6;
  const int r = blockIdx.x * 4 + rq;   // 0..2047
  const int b = r >> 9;
  const int n = r & 511;
  const float4* a4 = reinterpret_cast<const float4*>(agg + r * DD);
  const float4* x4 = reinterpret_cast<const float4*>(X + r * DD);
  float t0 = 0.f, t1 = 0.f, t2 = 0.f, t3 = 0.f;
#pragma unroll
  for (int c = 0; c < 16; ++c) {
    const float4 av = a4[c];
    const float4 xv = x4[c];
    t0 = fmaf(av.x, W_pa[(4 * c + 0) * DD + lane], t0);
    t1 = fmaf(av.y, W_pa[(4 * c + 1) * DD + lane], t1);
    t2 = fmaf(av.z, W_pa[(4 * c + 2) * DD + lane], t2);
    t3 = fmaf(av.w, W_pa[(4 * c + 3) * DD + lane], t3);
    t0 = fmaf(xv.x, W_po[(4 * c + 0) * DD + lane], t0);
    t1 = fmaf(xv.y, W_po[(4 * c + 1) * DD + lane], t1);
    t2 = fmaf(xv.z, W_po[(4 * c + 2) * DD + lane], t2);
    t3 = fmaf(xv.w, W_po[(4 * c + 3) * DD + lane], t3);
  }
  float y = ((t0 + t1) + (t2 + t3)) + b_pa[lane] + b_po[lane];
  const float RSQ = 0.9999950000374997f;   // 1/sqrt(1+1e-5)
  y = y * RSQ * gamma[lane] + beta[lane];
  const float SC = 1.0507009873554805f;
  const float AL = 1.6732632423543772f;
  y = (y > 0.f) ? (SC * y) : (SC * AL * expm1f(y));
  const int off = (n < NH) ? ((b * NH + n) * DD + lane)
                           : (BB * NH * DD + (b * NH + (n - NH)) * DD + lane);
  out[off] = y;
}

extern "C" void kernel_launch(void* const* d_in, const int* in_sizes, int n_in,
                              void* d_out, int out_size, void* d_ws, size_t ws_size,
                              hipStream_t stream) {
  const float* x1    = (const float*)d_in[0];
  const float* x2    = (const float*)d_in[1];
  const float* W_t1  = (const float*)d_in[2];
  const float* b_t1  = (const float*)d_in[3];
  const float* W_t2  = (const float*)d_in[4];
  const float* b_t2  = (const float*)d_in[5];
  const float* W_att = (const float*)d_in[6];
  const float* b_att = (const float*)d_in[7];
  const float* W_attM = (const float*)d_in[8];
  const float* b_attM = (const float*)d_in[9];
  const float* w11   = (const float*)d_in[10];
  const float* w22   = (const float*)d_in[11];
  const float* w12   = (const float*)d_in[12];
  const float* wM    = (const float*)d_in[13];
  const float* W_pa  = (const float*)d_in[14];
  const float* b_pa  = (const float*)d_in[15];
  const float* W_po  = (const float*)d_in[16];
  const float* b_po  = (const float*)d_in[17];
  const float* W_paM = (const float*)d_in[18];
  const float* b_paM = (const float*)d_in[19];
  const float* W_poM = (const float*)d_in[20];
  const float* b_poM = (const float*)d_in[21];
  const float* gamma = (const float*)d_in[22];
  const float* beta  = (const float*)d_in[23];

  float* ws     = (float*)d_ws;
  float* X      = ws;            // 131072 floats
  float* master = ws + 131072;   // 256
  float* logits = ws + 131328;   // 2048
  float* agg    = ws + 133376;   // 131072
  float* out    = (float*)d_out;

  k1_build_x<<<512, 256, 0, stream>>>(x1, x2, W_t1, b_t1, W_t2, b_t2, X);
  k2_master_mean<<<4, 256, 0, stream>>>(X, master);
  k3_att_agg<<<dim3(128, 4), 512, 0, stream>>>(X, W_att, b_att, w11, w22, w12, agg);
  k3b_mlogit<<<dim3(64, 4), 64, 0, stream>>>(X, master, W_attM, b_attM, wM, logits);
  k4_master_new<<<4, 256, 0, stream>>>(X, master, logits, W_paM, b_paM, W_poM, b_poM, out);
  k5_y<<<512, 256, 0, stream>>>(X, agg, W_pa, b_pa, W_po, b_po, gamma, beta, out);
}

// Round 2
// 98.199 us; speedup vs baseline: 6.5047x; 6.5047x over previous
//
#include <hip/hip_runtime.h>
#include <hip/hip_bf16.h>

#define BB 4
#define NN 512
#define NH 256
#define DD 64

typedef __attribute__((ext_vector_type(8))) short bf16x8;
typedef __attribute__((ext_vector_type(16))) float f32x16;

union BF8 { bf16x8 v; unsigned int u[4]; };

__device__ __forceinline__ float wred_sum(float v) {
  v += __shfl_xor(v, 32);
  v += __shfl_xor(v, 16);
  v += __shfl_xor(v, 8);
  v += __shfl_xor(v, 4);
  v += __shfl_xor(v, 2);
  v += __shfl_xor(v, 1);
  return v;
}

__device__ __forceinline__ float wred_max(float v) {
  v = fmaxf(v, __shfl_xor(v, 32));
  v = fmaxf(v, __shfl_xor(v, 16));
  v = fmaxf(v, __shfl_xor(v, 8));
  v = fmaxf(v, __shfl_xor(v, 4));
  v = fmaxf(v, __shfl_xor(v, 2));
  v = fmaxf(v, __shfl_xor(v, 1));
  return v;
}

__device__ __forceinline__ unsigned int cvtpk_bf16(float lo, float hi) {
  unsigned int r;
  asm("v_cvt_pk_bf16_f32 %0, %1, %2" : "=v"(r) : "v"(lo), "v"(hi));
  return r;
}

// tanh(t) = 1 - 2/(exp(2t)+1)
__device__ __forceinline__ float fast_tanh(float t) {
  t = fminf(15.f, fmaxf(-15.f, t));
  float z = __expf(2.f * t);
  return 1.f - 2.f * __builtin_amdgcn_rcpf(z + 1.f);
}

// K1: x[b,n,:] = (n<256 ? x1@W_t1+b_t1 : x2@W_t2+b_t2)
__global__ __launch_bounds__(256)
void k1_build_x(const float* __restrict__ x1, const float* __restrict__ x2,
                const float* __restrict__ W_t1, const float* __restrict__ b_t1,
                const float* __restrict__ W_t2, const float* __restrict__ b_t2,
                float* __restrict__ X) {
  const int tid = threadIdx.x;
  const int lane = tid & 63;
  const int rq = tid >> 6;
  const int r = blockIdx.x * 4 + rq;   // 0..2047
  const int b = r >> 9;
  const int n = r & 511;
  const float* src; const float* W; const float* bias;
  if (n < NH) { src = x1 + (b * NH + n) * DD;        W = W_t1; bias = b_t1; }
  else        { src = x2 + (b * NH + (n - NH)) * DD; W = W_t2; bias = b_t2; }
  const float4* s4 = reinterpret_cast<const float4*>(src);
  float t0 = 0.f, t1 = 0.f, t2 = 0.f, t3 = 0.f;
#pragma unroll
  for (int c = 0; c < 16; ++c) {
    const float4 v = s4[c];
    t0 = fmaf(v.x, W[(4 * c + 0) * DD + lane], t0);
    t1 = fmaf(v.y, W[(4 * c + 1) * DD + lane], t1);
    t2 = fmaf(v.z, W[(4 * c + 2) * DD + lane], t2);
    t3 = fmaf(v.w, W[(4 * c + 3) * DD + lane], t3);
  }
  X[r * DD + lane] = ((t0 + t1) + (t2 + t3)) + bias[lane];
}

// K2: master[b,:] = mean_n x[b,n,:]
__global__ __launch_bounds__(256)
void k2_master_mean(const float* __restrict__ X, float* __restrict__ master) {
  const int b = blockIdx.x;
  const int tid = threadIdx.x;
  const int lane = tid & 63;
  const int q = tid >> 6;
  __shared__ float red[4][DD];
  float s = 0.f;
  for (int n = q; n < NN; n += 4)
    s += X[(b * NN + n) * DD + lane];
  red[q][lane] = s;
  __syncthreads();
  if (q == 0) {
    master[b * DD + lane] =
        (red[0][lane] + red[1][lane] + red[2][lane] + red[3][lane]) * (1.f / 512.f);
  }
}

// K3: fused scores (MFMA) -> softmax_j -> agg = att @ x.
// Block: (b, 8 target rows i), 512 thr = 8 waves; wave w owns j-chunk [64w,64w+64).
// Per i: T^T[o,j] = (diag(x_i) W_att)^T @ X^T via mfma_32x32x16_bf16, so j = lane.
__global__ __launch_bounds__(512, 2)
void k3_att_agg(const float* __restrict__ X,
                const float* __restrict__ W_att,
                const float* __restrict__ b_att,
                const float* __restrict__ w11,
                const float* __restrict__ w22,
                const float* __restrict__ w12,
                float* __restrict__ agg) {
  const int b = blockIdx.y;
  const int i0 = blockIdx.x * 8;
  const int tid = threadIdx.x;
  const int lane = tid & 63;
  const int w = tid >> 6;        // 0..7
  const int l31 = lane & 31;
  const int half = lane >> 5;
  const int j0 = w << 6;

  __shared__ float xs[8 * DD];   // the 8 x_i rows (fp32)
  __shared__ float sc[8][NN];    // scores, then att
  __shared__ float red[8][DD];
  __shared__ float reds[8];

  const float* __restrict__ Xb = X + b * NN * DD;

  // stage x_i rows
  xs[tid] = Xb[(i0 + (tid >> 6)) * DD + (tid & 63)];

  // ---- i-invariant fragments ----
  // B[jt][kt] = X^T frag: lane holds col j=j0+jt*32+l31, k-elems d=kt*16+half*8+e
  BF8 Bf[2][4];
#pragma unroll
  for (int jt = 0; jt < 2; ++jt)
#pragma unroll
    for (int kt = 0; kt < 4; ++kt) {
      const float* base = Xb + (j0 + jt * 32 + l31) * DD + kt * 16 + half * 8;
      const float4 a = *reinterpret_cast<const float4*>(base);
      const float4 c = *reinterpret_cast<const float4*>(base + 4);
      Bf[jt][kt].u[0] = cvtpk_bf16(a.x, a.y);
      Bf[jt][kt].u[1] = cvtpk_bf16(a.z, a.w);
      Bf[jt][kt].u[2] = cvtpk_bf16(c.x, c.y);
      Bf[jt][kt].u[3] = cvtpk_bf16(c.z, c.w);
    }

  // W packed bf16: Wp[ot][kt][p] = pack(W[d0,o], W[d0+1,o]), o = ot*32+l31
  unsigned int Wp[2][4][4];
#pragma unroll
  for (int ot = 0; ot < 2; ++ot)
#pragma unroll
    for (int kt = 0; kt < 4; ++kt)
#pragma unroll
      for (int p = 0; p < 4; ++p) {
        const int d0 = kt * 16 + half * 8 + 2 * p;
        const int o = ot * 32 + l31;
        Wp[ot][kt][p] = cvtpk_bf16(W_att[d0 * DD + o], W_att[(d0 + 1) * DD + o]);
      }

  // per-accreg o-coeffs: o(r) = ot*32 + (r&3) + 8*(r>>2) + 4*half
  const int itype = (i0 >= NH);
  const int jtype = (w >= 4);
  const float* wsel = itype ? (jtype ? w22 : w12) : (jtype ? w12 : w11);
  float wv[2][16], bb2[2][16];
#pragma unroll
  for (int ot = 0; ot < 2; ++ot)
#pragma unroll
    for (int r = 0; r < 16; ++r) {
      const int o = ot * 32 + (r & 3) + 8 * (r >> 2) + 4 * half;
      wv[ot][r] = wsel[o];
      bb2[ot][r] = 2.0f * b_att[o];
    }
  __syncthreads();

  // ---- phase 1: per-i MFMA scores ----
#pragma unroll 1
  for (int ii = 0; ii < 8; ++ii) {
    float p0 = 0.f, p1 = 0.f;
#pragma unroll
    for (int ot = 0; ot < 2; ++ot) {
      // A[kt] = MC_i^T frag: row o = ot*32+l31, k-elems d = kt*16+half*8+e,
      // value = x_i[d] * W[d,o]
      BF8 A[4];
#pragma unroll
      for (int kt = 0; kt < 4; ++kt) {
        const float4 xa = *reinterpret_cast<const float4*>(&xs[ii * DD + kt * 16 + half * 8]);
        const float4 xc = *reinterpret_cast<const float4*>(&xs[ii * DD + kt * 16 + half * 8 + 4]);
#pragma unroll
        for (int p = 0; p < 4; ++p) {
          const unsigned int wp = Wp[ot][kt][p];
          const float w0 = __uint_as_float(wp << 16);
          const float w1 = __uint_as_float(wp & 0xFFFF0000u);
          const float xlo = (p < 2) ? ((p == 0) ? xa.x : xa.z) : ((p == 2) ? xc.x : xc.z);
          const float xhi = (p < 2) ? ((p == 0) ? xa.y : xa.w) : ((p == 2) ? xc.y : xc.w);
          A[kt].u[p] = cvtpk_bf16(xlo * w0, xhi * w1);
        }
      }
      f32x16 C0 = {};
      f32x16 C1 = {};
#pragma unroll
      for (int kt = 0; kt < 4; ++kt) {
        C0 = __builtin_amdgcn_mfma_f32_32x32x16_bf16(A[kt].v, Bf[0][kt].v, C0, 0, 0, 0);
        C1 = __builtin_amdgcn_mfma_f32_32x32x16_bf16(A[kt].v, Bf[1][kt].v, C1, 0, 0, 0);
      }
#pragma unroll
      for (int r = 0; r < 16; ++r) {
        // tanh(C + b) = 1 - 2/(exp(2C + 2b) + 1)
        const float e0 = __expf(fmaf(C0[r], 2.f, bb2[ot][r]));
        const float th0 = 1.f - 2.f * __builtin_amdgcn_rcpf(e0 + 1.f);
        p0 = fmaf(wv[ot][r], th0, p0);
        const float e1 = __expf(fmaf(C1[r], 2.f, bb2[ot][r]));
        const float th1 = 1.f - 2.f * __builtin_amdgcn_rcpf(e1 + 1.f);
        p1 = fmaf(wv[ot][r], th1, p1);
      }
    }
    // lane halves hold complementary o-rows for the same j-column
    p0 += __shfl_xor(p0, 32);
    p1 += __shfl_xor(p1, 32);
    sc[ii][j0 + lane] = (lane < 32) ? p0 : p1;   // j = j0 + lane
  }
  __syncthreads();

  // ---- phase 2: softmax over j (512) + agg rows ----
  for (int ii = 0; ii < 8; ++ii) {
    const float v = sc[ii][tid];
    float wm = wred_max(v);
    if (lane == 0) reds[w] = wm;
    __syncthreads();
    float bm = reds[0];
#pragma unroll
    for (int k = 1; k < 8; ++k) bm = fmaxf(bm, reds[k]);
    const float e = __expf(v - bm);
    float wsm = wred_sum(e);
    __syncthreads();
    if (lane == 0) reds[w] = wsm;
    __syncthreads();
    float bs = reds[0];
#pragma unroll
    for (int k = 1; k < 8; ++k) bs += reds[k];
    sc[ii][tid] = e * (1.f / bs);   // own-wave range; no barrier needed before reads

    float acc = 0.f;
    for (int jj = 0; jj < 64; ++jj)
      acc = fmaf(sc[ii][j0 + jj], Xb[(j0 + jj) * DD + lane], acc);
    red[w][lane] = acc;
    __syncthreads();
    if (w == 0) {
      float s = 0.f;
#pragma unroll
      for (int k = 0; k < 8; ++k) s += red[k][lane];
      agg[(b * NN + i0 + ii) * DD + lane] = s;
    }
    __syncthreads();
  }
}

// K3b: logits[b,i] = wM . tanh((x_i * master) @ W_attM + b_attM)
__global__ __launch_bounds__(64)
void k3b_mlogit(const float* __restrict__ X, const float* __restrict__ master,
                const float* __restrict__ W_attM, const float* __restrict__ b_attM,
                const float* __restrict__ wM, float* __restrict__ logits) {
  const int b = blockIdx.y;
  const int lane = threadIdx.x;
  const float bl = b_attM[lane];
  const float wl = wM[lane];
  const float4* m4 = reinterpret_cast<const float4*>(master + b * DD);
  for (int k = 0; k < 8; ++k) {
    const int i = blockIdx.x * 8 + k;
    const float4* xi4 = reinterpret_cast<const float4*>(X + (b * NN + i) * DD);
    float t0 = 0.f, t1 = 0.f, t2 = 0.f, t3 = 0.f;
#pragma unroll
    for (int c = 0; c < 16; ++c) {
      const float4 xv = xi4[c];
      const float4 mv = m4[c];
      t0 = fmaf(xv.x * mv.x, W_attM[(4 * c + 0) * DD + lane], t0);
      t1 = fmaf(xv.y * mv.y, W_attM[(4 * c + 1) * DD + lane], t1);
      t2 = fmaf(xv.z * mv.z, W_attM[(4 * c + 2) * DD + lane], t2);
      t3 = fmaf(xv.w * mv.w, W_attM[(4 * c + 3) * DD + lane], t3);
    }
    const float e = fast_tanh(((t0 + t1) + (t2 + t3)) + bl);
    const float s = wred_sum(e * wl);
    if (lane == 0) logits[b * NN + i] = s;
  }
}

// K4: softmax_n(logits) -> agg_m -> master_new (tail of out)
__global__ __launch_bounds__(256)
void k4_master_new(const float* __restrict__ X, const float* __restrict__ master,
                   const float* __restrict__ logits,
                   const float* __restrict__ W_paM, const float* __restrict__ b_paM,
                   const float* __restrict__ W_poM, const float* __restrict__ b_poM,
                   float* __restrict__ out) {
  const int b = blockIdx.x;
  const int tid = threadIdx.x;
  const int lane = tid & 63;
  const int q = tid >> 6;
  __shared__ float red[4][DD];
  __shared__ float r4[4];
  __shared__ float aggm_s[DD];
  __shared__ float mrow_s[DD];
  const float* lg = logits + b * NN;
  const float v0 = lg[tid];
  const float v1 = lg[tid + 256];
  float mx = wred_max(fmaxf(v0, v1));
  if (lane == 0) r4[q] = mx;
  __syncthreads();
  mx = fmaxf(fmaxf(r4[0], r4[1]), fmaxf(r4[2], r4[3]));
  float es = __expf(v0 - mx) + __expf(v1 - mx);
  es = wred_sum(es);
  __syncthreads();
  if (lane == 0) r4[q] = es;
  __syncthreads();
  const float S = r4[0] + r4[1] + r4[2] + r4[3];
  const float invS = 1.f / S;

  float acc = 0.f;
  for (int nn = q * 128; nn < q * 128 + 128; ++nn) {
    const float a = __expf(lg[nn] - mx);
    acc = fmaf(a, X[(b * NN + nn) * DD + lane], acc);
  }
  red[q][lane] = acc;
  __syncthreads();
  if (q == 0) {
    aggm_s[lane] =
        (red[0][lane] + red[1][lane] + red[2][lane] + red[3][lane]) * invS;
    mrow_s[lane] = master[b * DD + lane];
  }
  __syncthreads();
  float p = 0.f;
  for (int d = q * 16; d < q * 16 + 16; ++d) {
    p = fmaf(aggm_s[d], W_paM[d * DD + lane], p);
    p = fmaf(mrow_s[d], W_poM[d * DD + lane], p);
  }
  __syncthreads();
  red[q][lane] = p;
  __syncthreads();
  if (q == 0) {
    out[2 * BB * NH * DD + b * DD + lane] =
        red[0][lane] + red[1][lane] + red[2][lane] + red[3][lane] +
        b_paM[lane] + b_poM[lane];
  }
}

// K5: y = selu(BN(agg@W_pa + x@W_po + biases)), split-written to out
__global__ __launch_bounds__(256)
void k5_y(const float* __restrict__ X, const float* __restrict__ agg,
          const float* __restrict__ W_pa, const float* __restrict__ b_pa,
          const float* __restrict__ W_po, const float* __restrict__ b_po,
          const float* __restrict__ gamma, const float* __restrict__ beta,
          float* __restrict__ out) {
  const int tid = threadIdx.x;
  const int lane = tid & 63;
  const int rq = tid >> 6;
  const int r = blockIdx.x * 4 + rq;   // 0..2047
  const int b = r >> 9;
  const int n = r & 511;
  const float4* a4 = reinterpret_cast<const float4*>(agg + r * DD);
  const float4* x4 = reinterpret_cast<const float4*>(X + r * DD);
  float t0 = 0.f, t1 = 0.f, t2 = 0.f, t3 = 0.f;
#pragma unroll
  for (int c = 0; c < 16; ++c) {
    const float4 av = a4[c];
    const float4 xv = x4[c];
    t0 = fmaf(av.x, W_pa[(4 * c + 0) * DD + lane], t0);
    t1 = fmaf(av.y, W_pa[(4 * c + 1) * DD + lane], t1);
    t2 = fmaf(av.z, W_pa[(4 * c + 2) * DD + lane], t2);
    t3 = fmaf(av.w, W_pa[(4 * c + 3) * DD + lane], t3);
    t0 = fmaf(xv.x, W_po[(4 * c + 0) * DD + lane], t0);
    t1 = fmaf(xv.y, W_po[(4 * c + 1) * DD + lane], t1);
    t2 = fmaf(xv.z, W_po[(4 * c + 2) * DD + lane], t2);
    t3 = fmaf(xv.w, W_po[(4 * c + 3) * DD + lane], t3);
  }
  float y = ((t0 + t1) + (t2 + t3)) + b_pa[lane] + b_po[lane];
  const float RSQ = 0.9999950000374997f;   // 1/sqrt(1+1e-5)
  y = y * RSQ * gamma[lane] + beta[lane];
  const float SC = 1.0507009873554805f;
  const float AL = 1.6732632423543772f;
  y = (y > 0.f) ? (SC * y) : (SC * AL * expm1f(y));
  const int off = (n < NH) ? ((b * NH + n) * DD + lane)
                           : (BB * NH * DD + (b * NH + (n - NH)) * DD + lane);
  out[off] = y;
}

extern "C" void kernel_launch(void* const* d_in, const int* in_sizes, int n_in,
                              void* d_out, int out_size, void* d_ws, size_t ws_size,
                              hipStream_t stream) {
  const float* x1    = (const float*)d_in[0];
  const float* x2    = (const float*)d_in[1];
  const float* W_t1  = (const float*)d_in[2];
  const float* b_t1  = (const float*)d_in[3];
  const float* W_t2  = (const float*)d_in[4];
  const float* b_t2  = (const float*)d_in[5];
  const float* W_att = (const float*)d_in[6];
  const float* b_att = (const float*)d_in[7];
  const float* W_attM = (const float*)d_in[8];
  const float* b_attM = (const float*)d_in[9];
  const float* w11   = (const float*)d_in[10];
  const float* w22   = (const float*)d_in[11];
  const float* w12   = (const float*)d_in[12];
  const float* wM    = (const float*)d_in[13];
  const float* W_pa  = (const float*)d_in[14];
  const float* b_pa  = (const float*)d_in[15];
  const float* W_po  = (const float*)d_in[16];
  const float* b_po  = (const float*)d_in[17];
  const float* W_paM = (const float*)d_in[18];
  const float* b_paM = (const float*)d_in[19];
  const float* W_poM = (const float*)d_in[20];
  const float* b_poM = (const float*)d_in[21];
  const float* gamma = (const float*)d_in[22];
  const float* beta  = (const float*)d_in[23];

  float* ws     = (float*)d_ws;
  float* X      = ws;            // 131072 floats
  float* master = ws + 131072;   // 256
  float* logits = ws + 131328;   // 2048
  float* agg    = ws + 133376;   // 131072
  float* out    = (float*)d_out;

  k1_build_x<<<512, 256, 0, stream>>>(x1, x2, W_t1, b_t1, W_t2, b_t2, X);
  k2_master_mean<<<4, 256, 0, stream>>>(X, master);
  k3_att_agg<<<dim3(64, 4), 512, 0, stream>>>(X, W_att, b_att, w11, w22, w12, agg);
  k3b_mlogit<<<dim3(64, 4), 64, 0, stream>>>(X, master, W_attM, b_attM, wM, logits);
  k4_master_new<<<4, 256, 0, stream>>>(X, master, logits, W_paM, b_paM, W_poM, b_poM, out);
  k5_y<<<512, 256, 0, stream>>>(X, agg, W_pa, b_pa, W_po, b_po, gamma, beta, out);
}

// Round 3
// 84.642 us; speedup vs baseline: 7.5466x; 1.1602x over previous
//
#include <hip/hip_runtime.h>

#define BB 4
#define NN 512
#define NH 256
#define DD 64

typedef __attribute__((ext_vector_type(8))) short bf16x8;
typedef __attribute__((ext_vector_type(16))) float f32x16;
union BF8 { bf16x8 v; unsigned int u[4]; };

__device__ __forceinline__ float wred_sum(float v) {
  v += __shfl_xor(v, 32);
  v += __shfl_xor(v, 16);
  v += __shfl_xor(v, 8);
  v += __shfl_xor(v, 4);
  v += __shfl_xor(v, 2);
  v += __shfl_xor(v, 1);
  return v;
}

__device__ __forceinline__ float wred_max(float v) {
  v = fmaxf(v, __shfl_xor(v, 32));
  v = fmaxf(v, __shfl_xor(v, 16));
  v = fmaxf(v, __shfl_xor(v, 8));
  v = fmaxf(v, __shfl_xor(v, 4));
  v = fmaxf(v, __shfl_xor(v, 2));
  v = fmaxf(v, __shfl_xor(v, 1));
  return v;
}

__device__ __forceinline__ unsigned int cvtpk_bf16(float lo, float hi) {
  unsigned int r;
  asm("v_cvt_pk_bf16_f32 %0, %1, %2" : "=v"(r) : "v"(lo), "v"(hi));
  return r;
}

// v_exp_f32 computes 2^x
__device__ __forceinline__ float fast_exp2(float x) {
  float r;
  asm("v_exp_f32 %0, %1" : "=v"(r) : "v"(x));
  return r;
}

// tanh(t) = 1 - 2/(exp(2t)+1)
__device__ __forceinline__ float fast_tanh(float t) {
  t = fminf(15.f, fmaxf(-15.f, t));
  float z = __expf(2.f * t);
  return 1.f - 2.f * __builtin_amdgcn_rcpf(z + 1.f);
}

// K1: x[b,n,:] = (n<256 ? x1@W_t1+b_t1 : x2@W_t2+b_t2)
__global__ __launch_bounds__(256)
void k1_build_x(const float* __restrict__ x1, const float* __restrict__ x2,
                const float* __restrict__ W_t1, const float* __restrict__ b_t1,
                const float* __restrict__ W_t2, const float* __restrict__ b_t2,
                float* __restrict__ X) {
  const int tid = threadIdx.x;
  const int lane = tid & 63;
  const int rq = tid >> 6;
  const int r = blockIdx.x * 4 + rq;   // 0..2047
  const int b = r >> 9;
  const int n = r & 511;
  const float* src; const float* W; const float* bias;
  if (n < NH) { src = x1 + (b * NH + n) * DD;        W = W_t1; bias = b_t1; }
  else        { src = x2 + (b * NH + (n - NH)) * DD; W = W_t2; bias = b_t2; }
  const float4* s4 = reinterpret_cast<const float4*>(src);
  float t0 = 0.f, t1 = 0.f, t2 = 0.f, t3 = 0.f;
#pragma unroll
  for (int c = 0; c < 16; ++c) {
    const float4 v = s4[c];
    t0 = fmaf(v.x, W[(4 * c + 0) * DD + lane], t0);
    t1 = fmaf(v.y, W[(4 * c + 1) * DD + lane], t1);
    t2 = fmaf(v.z, W[(4 * c + 2) * DD + lane], t2);
    t3 = fmaf(v.w, W[(4 * c + 3) * DD + lane], t3);
  }
  X[r * DD + lane] = ((t0 + t1) + (t2 + t3)) + bias[lane];
}

// K2: master[b,:] = mean_n x[b,n,:]
__global__ __launch_bounds__(256)
void k2_master_mean(const float* __restrict__ X, float* __restrict__ master) {
  const int b = blockIdx.x;
  const int tid = threadIdx.x;
  const int lane = tid & 63;
  const int q = tid >> 6;
  __shared__ float red[4][DD];
  float s = 0.f;
  for (int n = q; n < NN; n += 4)
    s += X[(b * NN + n) * DD + lane];
  red[q][lane] = s;
  __syncthreads();
  if (q == 0) {
    master[b * DD + lane] =
        (red[0][lane] + red[1][lane] + red[2][lane] + red[3][lane]) * (1.f / 512.f);
  }
}

// K3: fused scores(MFMA) -> softmax -> agg -> y(selu) + logits.
// Block: (b, 8 rows). 8 waves; wave w owns j-chunk [64w,64w+64) in phase 1,
// and owns row i0+w entirely in phase 2.
__global__ __launch_bounds__(512, 1)
void k3_fused(const float* __restrict__ X, const float* __restrict__ master,
              const float* __restrict__ W_att, const float* __restrict__ b_att,
              const float* __restrict__ w11, const float* __restrict__ w22,
              const float* __restrict__ w12,
              const float* __restrict__ W_attM, const float* __restrict__ b_attM,
              const float* __restrict__ wM,
              const float* __restrict__ W_pa, const float* __restrict__ b_pa,
              const float* __restrict__ W_po, const float* __restrict__ b_po,
              const float* __restrict__ gamma, const float* __restrict__ beta,
              float* __restrict__ logits, float* __restrict__ out) {
  const int b = blockIdx.y;
  const int i0 = blockIdx.x * 8;
  const int tid = threadIdx.x;
  const int lane = tid & 63;
  const int w = tid >> 6;        // 0..7
  const int l31 = lane & 31;
  const int half = lane >> 5;
  const int j0 = w << 6;

  __shared__ float Xlds[NN * DD];   // 128 KB
  __shared__ float sc[8 * NN];      // 16 KB

  const float* __restrict__ Xb = X + b * NN * DD;

  // ---- stage X[b] into LDS (coalesced float4, conflict-free writes) ----
  {
    const int c4 = (tid & 15) * 4;
    const int rh = tid >> 4;        // 0..31
#pragma unroll
    for (int it = 0; it < 16; ++it) {
      const int r = it * 32 + rh;
      *reinterpret_cast<float4*>(&Xlds[r * DD + c4]) =
          *reinterpret_cast<const float4*>(&Xb[r * DD + c4]);
    }
  }

  // ---- i-invariant register state (global reads; overlaps staging) ----
  // A-frags: W^T, row o = ot*32+l31, k-elem d = kt*16+half*8+e
  BF8 Wp[2][4];
#pragma unroll
  for (int ot = 0; ot < 2; ++ot)
#pragma unroll
    for (int kt = 0; kt < 4; ++kt) {
      const int o = ot * 32 + l31;
#pragma unroll
      for (int p = 0; p < 4; ++p) {
        const int d0 = kt * 16 + half * 8 + 2 * p;
        Wp[ot][kt].u[p] = cvtpk_bf16(W_att[d0 * DD + o], W_att[(d0 + 1) * DD + o]);
      }
    }

  // x_j rows fp32: col j = j0+jt*32+l31, d = kt*16+half*8+e
  float Xf[2][4][8];
#pragma unroll
  for (int jt = 0; jt < 2; ++jt)
#pragma unroll
    for (int kt = 0; kt < 4; ++kt) {
      const float* base = Xb + (j0 + jt * 32 + l31) * DD + kt * 16 + half * 8;
      *reinterpret_cast<float4*>(&Xf[jt][kt][0]) = *reinterpret_cast<const float4*>(base);
      *reinterpret_cast<float4*>(&Xf[jt][kt][4]) = *reinterpret_cast<const float4*>(base + 4);
    }

  const int itype = (i0 >= NH);
  const int jtype = (w >= 4);
  const float* wsel = itype ? (jtype ? w22 : w12) : (jtype ? w12 : w11);
  const float K2E = 2.885390081777927f;  // 2*log2(e)
  float wv2[2][16], bk[2][16];
#pragma unroll
  for (int ot = 0; ot < 2; ++ot)
#pragma unroll
    for (int r = 0; r < 16; ++r) {
      const int o = ot * 32 + (r & 3) + 8 * (r >> 2) + 4 * half;
      wv2[ot][r] = -2.0f * wsel[o];
      bk[ot][r] = K2E * b_att[o];
    }
  const float swv = wred_sum(wsel[lane]);   // sum_o wsel[o], wave-uniform

  const float m_reg = master[b * DD + lane];
  const float wMl  = wM[lane];
  const float bAMl = b_attM[lane];
  const float ybias = b_pa[lane] + b_po[lane];
  const float gl = gamma[lane];
  const float btl = beta[lane];

  __syncthreads();

  // ---- phase 1: scores ----
#pragma unroll 1
  for (int ii = 0; ii < 8; ++ii) {
    // B-frags: bf16(x_i[d] * x_j[d]); built once per i, shared across ot
    BF8 Bi[2][4];
#pragma unroll
    for (int kt = 0; kt < 4; ++kt) {
      const float4 xa = *reinterpret_cast<const float4*>(&Xlds[(i0 + ii) * DD + kt * 16 + half * 8]);
      const float4 xc = *reinterpret_cast<const float4*>(&Xlds[(i0 + ii) * DD + kt * 16 + half * 8 + 4]);
#pragma unroll
      for (int jt = 0; jt < 2; ++jt) {
        Bi[jt][kt].u[0] = cvtpk_bf16(xa.x * Xf[jt][kt][0], xa.y * Xf[jt][kt][1]);
        Bi[jt][kt].u[1] = cvtpk_bf16(xa.z * Xf[jt][kt][2], xa.w * Xf[jt][kt][3]);
        Bi[jt][kt].u[2] = cvtpk_bf16(xc.x * Xf[jt][kt][4], xc.y * Xf[jt][kt][5]);
        Bi[jt][kt].u[3] = cvtpk_bf16(xc.z * Xf[jt][kt][6], xc.w * Xf[jt][kt][7]);
      }
    }
    float p0 = 0.f, p1 = 0.f;
#pragma unroll
    for (int ot = 0; ot < 2; ++ot) {
      f32x16 C0 = {}, C1 = {};
#pragma unroll
      for (int kt = 0; kt < 4; ++kt) {
        C0 = __builtin_amdgcn_mfma_f32_32x32x16_bf16(Wp[ot][kt].v, Bi[0][kt].v, C0, 0, 0, 0);
        C1 = __builtin_amdgcn_mfma_f32_32x32x16_bf16(Wp[ot][kt].v, Bi[1][kt].v, C1, 0, 0, 0);
      }
#pragma unroll
      for (int r = 0; r < 16; ++r) {
        // w*tanh(C+b) summed; tanh = 1 - 2*rcp(1+2^(K2E*(C+b))); sum_w in swv
        const float e0 = fast_exp2(fmaf(C0[r], K2E, bk[ot][r]));
        p0 = fmaf(wv2[ot][r], __builtin_amdgcn_rcpf(e0 + 1.f), p0);
        const float e1 = fast_exp2(fmaf(C1[r], K2E, bk[ot][r]));
        p1 = fmaf(wv2[ot][r], __builtin_amdgcn_rcpf(e1 + 1.f), p1);
      }
    }
    p0 += __shfl_xor(p0, 32);
    p1 += __shfl_xor(p1, 32);
    sc[ii * NN + j0 + lane] = swv + ((lane < 32) ? p0 : p1);
  }
  __syncthreads();

  // ---- phase 2: wave w owns row irow = i0 + w (no more block barriers) ----
  const int irow = i0 + w;
  float v[8];
#pragma unroll
  for (int k = 0; k < 8; ++k) v[k] = sc[w * NN + lane + 64 * k];
  float mx = v[0];
#pragma unroll
  for (int k = 1; k < 8; ++k) mx = fmaxf(mx, v[k]);
  mx = wred_max(mx);
  float ssum = 0.f;
#pragma unroll
  for (int k = 0; k < 8; ++k) { v[k] = __expf(v[k] - mx); ssum += v[k]; }
  ssum = wred_sum(ssum);
  const float inv = __builtin_amdgcn_rcpf(ssum);
#pragma unroll
  for (int k = 0; k < 8; ++k) sc[w * NN + lane + 64 * k] = v[k] * inv;

  // agg[irow][d=lane] = sum_j att[j] * X[j][d]
  float acc = 0.f;
  const float* scrow = &sc[w * NN];
  for (int j4 = 0; j4 < NN / 4; ++j4) {
    const float4 a4 = *reinterpret_cast<const float4*>(&scrow[j4 * 4]);
    acc = fmaf(a4.x, Xlds[(j4 * 4 + 0) * DD + lane], acc);
    acc = fmaf(a4.y, Xlds[(j4 * 4 + 1) * DD + lane], acc);
    acc = fmaf(a4.z, Xlds[(j4 * 4 + 2) * DD + lane], acc);
    acc = fmaf(a4.w, Xlds[(j4 * 4 + 3) * DD + lane], acc);
  }

  // fused k5: y = selu(BN(agg@W_pa + x@W_po + biases))
  const float xi = Xlds[irow * DD + lane];
  float y = ybias;
#pragma unroll 8
  for (int d = 0; d < DD; ++d) {
    y = fmaf(__shfl(acc, d), W_pa[d * DD + lane], y);
    y = fmaf(__shfl(xi, d),  W_po[d * DD + lane], y);
  }
  const float RSQ = 0.9999950000374997f;   // 1/sqrt(1+1e-5)
  y = y * RSQ * gl + btl;
  const float SC_ = 1.0507009873554805f;
  const float AL  = 1.6732632423543772f;
  y = (y > 0.f) ? (SC_ * y) : (SC_ * AL * (__expf(y) - 1.f));
  const int off = (irow < NH) ? ((b * NH + irow) * DD + lane)
                              : (BB * NH * DD + (b * NH + (irow - NH)) * DD + lane);
  out[off] = y;

  // fused k3b: logits[b,irow] = wM . tanh((x_i*master)@W_attM + b_attM)
  float lg = bAMl;
#pragma unroll 8
  for (int d = 0; d < DD; ++d) {
    const float xm = __shfl(xi, d) * __shfl(m_reg, d);
    lg = fmaf(xm, W_attM[d * DD + lane], lg);
  }
  const float th = fast_tanh(lg);
  const float s = wred_sum(th * wMl);
  if (lane == 0) logits[b * NN + irow] = s;
}

// K4: softmax_n(logits) -> agg_m -> master_new (tail of out)
__global__ __launch_bounds__(256)
void k4_master_new(const float* __restrict__ X, const float* __restrict__ master,
                   const float* __restrict__ logits,
                   const float* __restrict__ W_paM, const float* __restrict__ b_paM,
                   const float* __restrict__ W_poM, const float* __restrict__ b_poM,
                   float* __restrict__ out) {
  const int b = blockIdx.x;
  const int tid = threadIdx.x;
  const int lane = tid & 63;
  const int q = tid >> 6;
  __shared__ float red[4][DD];
  __shared__ float r4[4];
  __shared__ float aggm_s[DD];
  __shared__ float mrow_s[DD];
  const float* lg = logits + b * NN;
  const float v0 = lg[tid];
  const float v1 = lg[tid + 256];
  float mx = wred_max(fmaxf(v0, v1));
  if (lane == 0) r4[q] = mx;
  __syncthreads();
  mx = fmaxf(fmaxf(r4[0], r4[1]), fmaxf(r4[2], r4[3]));
  float es = __expf(v0 - mx) + __expf(v1 - mx);
  es = wred_sum(es);
  __syncthreads();
  if (lane == 0) r4[q] = es;
  __syncthreads();
  const float S = r4[0] + r4[1] + r4[2] + r4[3];
  const float invS = 1.f / S;

  float acc = 0.f;
  for (int nn = q * 128; nn < q * 128 + 128; ++nn) {
    const float a = __expf(lg[nn] - mx);
    acc = fmaf(a, X[(b * NN + nn) * DD + lane], acc);
  }
  red[q][lane] = acc;
  __syncthreads();
  if (q == 0) {
    aggm_s[lane] =
        (red[0][lane] + red[1][lane] + red[2][lane] + red[3][lane]) * invS;
    mrow_s[lane] = master[b * DD + lane];
  }
  __syncthreads();
  float p = 0.f;
  for (int d = q * 16; d < q * 16 + 16; ++d) {
    p = fmaf(aggm_s[d], W_paM[d * DD + lane], p);
    p = fmaf(mrow_s[d], W_poM[d * DD + lane], p);
  }
  __syncthreads();
  red[q][lane] = p;
  __syncthreads();
  if (q == 0) {
    out[2 * BB * NH * DD + b * DD + lane] =
        red[0][lane] + red[1][lane] + red[2][lane] + red[3][lane] +
        b_paM[lane] + b_poM[lane];
  }
}

extern "C" void kernel_launch(void* const* d_in, const int* in_sizes, int n_in,
                              void* d_out, int out_size, void* d_ws, size_t ws_size,
                              hipStream_t stream) {
  const float* x1    = (const float*)d_in[0];
  const float* x2    = (const float*)d_in[1];
  const float* W_t1  = (const float*)d_in[2];
  const float* b_t1  = (const float*)d_in[3];
  const float* W_t2  = (const float*)d_in[4];
  const float* b_t2  = (const float*)d_in[5];
  const float* W_att = (const float*)d_in[6];
  const float* b_att = (const float*)d_in[7];
  const float* W_attM = (const float*)d_in[8];
  const float* b_attM = (const float*)d_in[9];
  const float* w11   = (const float*)d_in[10];
  const float* w22   = (const float*)d_in[11];
  const float* w12   = (const float*)d_in[12];
  const float* wM    = (const float*)d_in[13];
  const float* W_pa  = (const float*)d_in[14];
  const float* b_pa  = (const float*)d_in[15];
  const float* W_po  = (const float*)d_in[16];
  const float* b_po  = (const float*)d_in[17];
  const float* W_paM = (const float*)d_in[18];
  const float* b_paM = (const float*)d_in[19];
  const float* W_poM = (const float*)d_in[20];
  const float* b_poM = (const float*)d_in[21];
  const float* gamma = (const float*)d_in[22];
  const float* beta  = (const float*)d_in[23];

  float* ws     = (float*)d_ws;
  float* X      = ws;            // 131072 floats
  float* master = ws + 131072;   // 256
  float* logits = ws + 131328;   // 2048
  float* out    = (float*)d_out;

  k1_build_x<<<512, 256, 0, stream>>>(x1, x2, W_t1, b_t1, W_t2, b_t2, X);
  k2_master_mean<<<4, 256, 0, stream>>>(X, master);
  k3_fused<<<dim3(64, 4), 512, 0, stream>>>(X, master, W_att, b_att, w11, w22, w12,
                                            W_attM, b_attM, wM, W_pa, b_pa, W_po, b_po,
                                            gamma, beta, logits, out);
  k4_master_new<<<4, 256, 0, stream>>>(X, master, logits, W_paM, b_paM, W_poM, b_poM, out);
}

// Round 6
// 52.203 us; speedup vs baseline: 12.2361x; 1.6214x over previous
//
#include <hip/hip_runtime.h>

#define BB 4
#define NN 512
#define NH 256
#define DD 64

typedef __attribute__((ext_vector_type(8))) short bf16x8;
typedef __attribute__((ext_vector_type(16))) float f32x16;
union BF8 { bf16x8 v; unsigned int u[4]; };

__device__ __forceinline__ float wred_sum(float v) {
  v += __shfl_xor(v, 32);
  v += __shfl_xor(v, 16);
  v += __shfl_xor(v, 8);
  v += __shfl_xor(v, 4);
  v += __shfl_xor(v, 2);
  v += __shfl_xor(v, 1);
  return v;
}

__device__ __forceinline__ float wred_max(float v) {
  v = fmaxf(v, __shfl_xor(v, 32));
  v = fmaxf(v, __shfl_xor(v, 16));
  v = fmaxf(v, __shfl_xor(v, 8));
  v = fmaxf(v, __shfl_xor(v, 4));
  v = fmaxf(v, __shfl_xor(v, 2));
  v = fmaxf(v, __shfl_xor(v, 1));
  return v;
}

__device__ __forceinline__ unsigned int cvtpk_bf16(float lo, float hi) {
  unsigned int r;
  asm("v_cvt_pk_bf16_f32 %0, %1, %2" : "=v"(r) : "v"(lo), "v"(hi));
  return r;
}

// v_exp_f32 computes 2^x
__device__ __forceinline__ float fast_exp2(float x) {
  float r;
  asm("v_exp_f32 %0, %1" : "=v"(r) : "v"(x));
  return r;
}

// tanh(t) = 1 - 2/(exp(2t)+1)
__device__ __forceinline__ float fast_tanh(float t) {
  t = fminf(15.f, fmaxf(-15.f, t));
  float z = __expf(2.f * t);
  return 1.f - 2.f * __builtin_amdgcn_rcpf(z + 1.f);
}

// K1: x[b,n,:] = (n<256 ? x1@W_t1+b_t1 : x2@W_t2+b_t2)
__global__ __launch_bounds__(256)
void k1_build_x(const float* __restrict__ x1, const float* __restrict__ x2,
                const float* __restrict__ W_t1, const float* __restrict__ b_t1,
                const float* __restrict__ W_t2, const float* __restrict__ b_t2,
                float* __restrict__ X) {
  const int tid = threadIdx.x;
  const int lane = tid & 63;
  const int rq = tid >> 6;
  const int r = blockIdx.x * 4 + rq;   // 0..2047
  const int b = r >> 9;
  const int n = r & 511;
  const float* src; const float* W; const float* bias;
  if (n < NH) { src = x1 + (b * NH + n) * DD;        W = W_t1; bias = b_t1; }
  else        { src = x2 + (b * NH + (n - NH)) * DD; W = W_t2; bias = b_t2; }
  const float4* s4 = reinterpret_cast<const float4*>(src);
  float t0 = 0.f, t1 = 0.f, t2 = 0.f, t3 = 0.f;
#pragma unroll
  for (int c = 0; c < 16; ++c) {
    const float4 v = s4[c];
    t0 = fmaf(v.x, W[(4 * c + 0) * DD + lane], t0);
    t1 = fmaf(v.y, W[(4 * c + 1) * DD + lane], t1);
    t2 = fmaf(v.z, W[(4 * c + 2) * DD + lane], t2);
    t3 = fmaf(v.w, W[(4 * c + 3) * DD + lane], t3);
  }
  X[r * DD + lane] = ((t0 + t1) + (t2 + t3)) + bias[lane];
}

// K3: staging + master-mean + scores(MFMA) + softmax + agg + y(selu) + logits.
// 1024 threads = 16 waves. Phase 1: wave w owns j-chunk [32w, 32w+32).
// Phase 2: wave (row = w&7, part = w>>3); part0 -> y-proj, part1 -> logits.
__global__ __launch_bounds__(1024, 1)
void k3_fused(const float* __restrict__ X,
              const float* __restrict__ W_att, const float* __restrict__ b_att,
              const float* __restrict__ w11, const float* __restrict__ w22,
              const float* __restrict__ w12,
              const float* __restrict__ W_attM, const float* __restrict__ b_attM,
              const float* __restrict__ wM,
              const float* __restrict__ W_pa, const float* __restrict__ b_pa,
              const float* __restrict__ W_po, const float* __restrict__ b_po,
              const float* __restrict__ gamma, const float* __restrict__ beta,
              float* __restrict__ master, float* __restrict__ logits,
              float* __restrict__ out) {
  const int b = blockIdx.y;
  const int i0 = blockIdx.x * 8;
  const int tid = threadIdx.x;
  const int lane = tid & 63;
  const int w = tid >> 6;        // 0..15
  const int l31 = lane & 31;
  const int half = lane >> 5;
  const int j0 = w << 5;         // 32-wide j chunk

  __shared__ __align__(16) float Xlds[NN * DD];   // 128 KB
  __shared__ __align__(16) float sc[8 * NN];      // 16 KB
  __shared__ __align__(16) float red2[16][DD];    // 4 KB
  __shared__ __align__(16) float aggL[8][DD];     // 2 KB
  __shared__ __align__(16) float tblB[64];        // K2E*b_att in C-reg order
  __shared__ __align__(16) float tblW[2][64];     // -2*wsel in C-reg order, per jtype
  __shared__ __align__(16) float mastL[64];

  const float* __restrict__ Xb = X + b * NN * DD;
  const float K2E = 2.8853900817779268f;  // 2*log2(e)
  const int itype = (i0 >= NH);
  const int jtype = (w >= 8);

  // ---- stage X[b] -> LDS ----
  {
    const int c4 = (tid & 15) * 4;
    const int rh = tid >> 4;        // 0..63
#pragma unroll
    for (int it = 0; it < 8; ++it) {
      const int r = it * 64 + rh;
      *reinterpret_cast<float4*>(&Xlds[r * DD + c4]) =
          *reinterpret_cast<const float4*>(&Xb[r * DD + c4]);
    }
  }
  // coefficient tables in MFMA C-layout order: idx = ot*32 + hf*16 + r
  if (tid < 64) {
    const int ot = tid >> 5, hf = (tid >> 4) & 1, r = tid & 15;
    const int o = ot * 32 + (r & 3) + 8 * (r >> 2) + 4 * hf;
    tblB[tid] = K2E * b_att[o];
  } else if (tid >= 128 && tid < 256) {
    const int t = tid - 128;
    const int jt = t >> 6;
    const int idx = t & 63;
    const int ot = idx >> 5, hf = (idx >> 4) & 1, r = idx & 15;
    const int o = ot * 32 + (r & 3) + 8 * (r >> 2) + 4 * hf;
    const float* wsl = itype ? (jt ? w22 : w12) : (jt ? w12 : w11);
    tblW[jt][idx] = -2.f * wsl[o];
  }

  // ---- i-invariant register state ----
  // A-frags: W^T (unscaled bf16), row o = ot*32+l31, k-elem d = kt*16+half*8+e
  BF8 Wp[2][4];
#pragma unroll
  for (int ot = 0; ot < 2; ++ot)
#pragma unroll
    for (int kt = 0; kt < 4; ++kt) {
      const int o = ot * 32 + l31;
#pragma unroll
      for (int p = 0; p < 4; ++p) {
        const int d0 = kt * 16 + half * 8 + 2 * p;
        Wp[ot][kt].u[p] = cvtpk_bf16(W_att[d0 * DD + o], W_att[(d0 + 1) * DD + o]);
      }
    }

  // x_j packed bf16: col j = j0+l31, d = kt*16+half*8+e
  BF8 Xf[4];
#pragma unroll
  for (int kt = 0; kt < 4; ++kt) {
    const float* base = Xb + (j0 + l31) * DD + kt * 16 + half * 8;
    const float4 a = *reinterpret_cast<const float4*>(base);
    const float4 c = *reinterpret_cast<const float4*>(base + 4);
    Xf[kt].u[0] = cvtpk_bf16(a.x, a.y);
    Xf[kt].u[1] = cvtpk_bf16(a.z, a.w);
    Xf[kt].u[2] = cvtpk_bf16(c.x, c.y);
    Xf[kt].u[3] = cvtpk_bf16(c.z, c.w);
  }

  const float* wsel = itype ? (jtype ? w22 : w12) : (jtype ? w12 : w11);
  const float swv = wred_sum(wsel[lane]);   // sum_o wsel[o], wave-uniform

  __syncthreads();   // bar1: Xlds + tables ready

  // ---- master mean (fused k2): wave w sums rows [32w, 32w+32) ----
  {
    float s = 0.f;
    for (int r = w * 32; r < w * 32 + 32; ++r) s += Xlds[r * DD + lane];
    red2[w][lane] = s;
  }
  __syncthreads();   // bar2
  if (w == 0) {
    float s = 0.f;
#pragma unroll
    for (int k = 0; k < 16; ++k) s += red2[k][lane];
    s *= (1.f / 512.f);
    mastL[lane] = s;
    if (blockIdx.x == 0) master[b * DD + lane] = s;
  }

  // ---- phase 1: scores for 8 rows (R3-verified f32 epilogue) ----
#pragma unroll 1
  for (int ii = 0; ii < 8; ++ii) {
    // B-frags: bf16(x_i[d] * x_j[d])
    BF8 Bi[4];
#pragma unroll
    for (int kt = 0; kt < 4; ++kt) {
      const float4 xa = *reinterpret_cast<const float4*>(&Xlds[(i0 + ii) * DD + kt * 16 + half * 8]);
      const float4 xc = *reinterpret_cast<const float4*>(&Xlds[(i0 + ii) * DD + kt * 16 + half * 8 + 4]);
      unsigned int u;
      u = Xf[kt].u[0];
      Bi[kt].u[0] = cvtpk_bf16(xa.x * __uint_as_float(u << 16),
                               xa.y * __uint_as_float(u & 0xffff0000u));
      u = Xf[kt].u[1];
      Bi[kt].u[1] = cvtpk_bf16(xa.z * __uint_as_float(u << 16),
                               xa.w * __uint_as_float(u & 0xffff0000u));
      u = Xf[kt].u[2];
      Bi[kt].u[2] = cvtpk_bf16(xc.x * __uint_as_float(u << 16),
                               xc.y * __uint_as_float(u & 0xffff0000u));
      u = Xf[kt].u[3];
      Bi[kt].u[3] = cvtpk_bf16(xc.z * __uint_as_float(u << 16),
                               xc.w * __uint_as_float(u & 0xffff0000u));
    }
    float ptot = 0.f;
#pragma unroll
    for (int ot = 0; ot < 2; ++ot) {
      f32x16 C = {};
#pragma unroll
      for (int kt = 0; kt < 4; ++kt)
        C = __builtin_amdgcn_mfma_f32_32x32x16_bf16(Wp[ot][kt].v, Bi[kt].v, C, 0, 0, 0);
      const int base = ot * 32 + half * 16;
      float p = 0.f;
#pragma unroll
      for (int r = 0; r < 16; ++r) {
        // w*tanh(C+b): arg = K2E*(C+b); p += (-2w)*rcp(2^arg + 1); +sum_w later
        const float arg = fmaf(C[r], K2E, tblB[base + r]);
        const float e = fast_exp2(arg);
        p = fmaf(tblW[jtype][base + r], __builtin_amdgcn_rcpf(e + 1.f), p);
      }
      ptot += p;
    }
    ptot += __shfl_xor(ptot, 32);   // combine o-halves
    if (lane < 32) sc[ii * NN + j0 + l31] = swv + ptot;
  }
  __syncthreads();   // bar3: scores + mastL ready

  // ---- phase 2: 2 waves per row ----
  const int row = w & 7, part = w >> 3;
  const int irow = i0 + row;
  float v[8];
#pragma unroll
  for (int k = 0; k < 8; ++k) v[k] = sc[row * NN + lane + 64 * k];
  __syncthreads();   // bar3b: all score reads done before att overwrite
  float mx = fmaxf(fmaxf(fmaxf(v[0], v[1]), fmaxf(v[2], v[3])),
                   fmaxf(fmaxf(v[4], v[5]), fmaxf(v[6], v[7])));
  mx = wred_max(mx);
  float ssum = 0.f;
#pragma unroll
  for (int k = 0; k < 8; ++k) { v[k] = __expf(v[k] - mx); ssum += v[k]; }
  ssum = wred_sum(ssum);
  const float inv = __builtin_amdgcn_rcpf(ssum);
#pragma unroll
  for (int k = 0; k < 4; ++k) {
    const int kk = part * 4 + k;
    sc[row * NN + lane + 64 * kk] = v[kk] * inv;
  }

  // agg partial over own j-half
  float a0 = 0.f, a1 = 0.f, a2 = 0.f, a3 = 0.f;
  const float* scr = &sc[row * NN + part * 256];
  const int xof = part * 256 * DD;
  for (int jj = 0; jj < 64; ++jj) {
    const float4 at = *reinterpret_cast<const float4*>(&scr[jj * 4]);
    a0 = fmaf(at.x, Xlds[xof + (jj * 4 + 0) * DD + lane], a0);
    a1 = fmaf(at.y, Xlds[xof + (jj * 4 + 1) * DD + lane], a1);
    a2 = fmaf(at.z, Xlds[xof + (jj * 4 + 2) * DD + lane], a2);
    a3 = fmaf(at.w, Xlds[xof + (jj * 4 + 3) * DD + lane], a3);
  }
  red2[w][lane] = (a0 + a1) + (a2 + a3);
  __syncthreads();   // bar4

  if (part == 0) {
    // y = selu(BN(agg@W_pa + x@W_po + biases))
    const float aggv = red2[w][lane] + red2[w + 8][lane];
    aggL[row][lane] = aggv;
    float y = b_pa[lane] + b_po[lane];
#pragma unroll 8
    for (int d = 0; d < DD; ++d) {
      y = fmaf(aggL[row][d], W_pa[d * DD + lane], y);
      y = fmaf(Xlds[irow * DD + d], W_po[d * DD + lane], y);
    }
    const float RSQ = 0.9999950000374997f;   // 1/sqrt(1+1e-5)
    y = y * RSQ * gamma[lane] + beta[lane];
    const float SC_ = 1.0507009873554805f;
    const float AL = 1.6732632423543772f;
    y = (y > 0.f) ? (SC_ * y) : (SC_ * AL * (__expf(y) - 1.f));
    const int off = (irow < NH) ? ((b * NH + irow) * DD + lane)
                                : (BB * NH * DD + (b * NH + (irow - NH)) * DD + lane);
    out[off] = y;
  } else {
    // logits[b,irow] = wM . tanh((x_i*master)@W_attM + b_attM)
    float lg = b_attM[lane];
#pragma unroll 8
    for (int d = 0; d < DD; ++d)
      lg = fmaf(Xlds[irow * DD + d] * mastL[d], W_attM[d * DD + lane], lg);
    const float th = fast_tanh(lg);
    const float s = wred_sum(th * wM[lane]);
    if (lane == 0) logits[b * NN + irow] = s;
  }
}

// K4: softmax_n(logits) -> agg_m -> master_new (tail of out)
__global__ __launch_bounds__(256)
void k4_master_new(const float* __restrict__ X, const float* __restrict__ master,
                   const float* __restrict__ logits,
                   const float* __restrict__ W_paM, const float* __restrict__ b_paM,
                   const float* __restrict__ W_poM, const float* __restrict__ b_poM,
                   float* __restrict__ out) {
  const int b = blockIdx.x;
  const int tid = threadIdx.x;
  const int lane = tid & 63;
  const int q = tid >> 6;
  __shared__ float red[4][DD];
  __shared__ float r4[4];
  __shared__ float aggm_s[DD];
  __shared__ float mrow_s[DD];
  const float* lg = logits + b * NN;
  const float v0 = lg[tid];
  const float v1 = lg[tid + 256];
  float mx = wred_max(fmaxf(v0, v1));
  if (lane == 0) r4[q] = mx;
  __syncthreads();
  mx = fmaxf(fmaxf(r4[0], r4[1]), fmaxf(r4[2], r4[3]));
  float es = __expf(v0 - mx) + __expf(v1 - mx);
  es = wred_sum(es);
  __syncthreads();
  if (lane == 0) r4[q] = es;
  __syncthreads();
  const float S = r4[0] + r4[1] + r4[2] + r4[3];
  const float invS = 1.f / S;

  float acc = 0.f;
  for (int nn = q * 128; nn < q * 128 + 128; ++nn) {
    const float a = __expf(lg[nn] - mx);
    acc = fmaf(a, X[(b * NN + nn) * DD + lane], acc);
  }
  red[q][lane] = acc;
  __syncthreads();
  if (q == 0) {
    aggm_s[lane] =
        (red[0][lane] + red[1][lane] + red[2][lane] + red[3][lane]) * invS;
    mrow_s[lane] = master[b * DD + lane];
  }
  __syncthreads();
  float p = 0.f;
  for (int d = q * 16; d < q * 16 + 16; ++d) {
    p = fmaf(aggm_s[d], W_paM[d * DD + lane], p);
    p = fmaf(mrow_s[d], W_poM[d * DD + lane], p);
  }
  __syncthreads();
  red[q][lane] = p;
  __syncthreads();
  if (q == 0) {
    out[2 * BB * NH * DD + b * DD + lane] =
        red[0][lane] + red[1][lane] + red[2][lane] + red[3][lane] +
        b_paM[lane] + b_poM[lane];
  }
}

extern "C" void kernel_launch(void* const* d_in, const int* in_sizes, int n_in,
                              void* d_out, int out_size, void* d_ws, size_t ws_size,
                              hipStream_t stream) {
  const float* x1    = (const float*)d_in[0];
  const float* x2    = (const float*)d_in[1];
  const float* W_t1  = (const float*)d_in[2];
  const float* b_t1  = (const float*)d_in[3];
  const float* W_t2  = (const float*)d_in[4];
  const float* b_t2  = (const float*)d_in[5];
  const float* W_att = (const float*)d_in[6];
  const float* b_att = (const float*)d_in[7];
  const float* W_attM = (const float*)d_in[8];
  const float* b_attM = (const float*)d_in[9];
  const float* w11   = (const float*)d_in[10];
  const float* w22   = (const float*)d_in[11];
  const float* w12   = (const float*)d_in[12];
  const float* wM    = (const float*)d_in[13];
  const float* W_pa  = (const float*)d_in[14];
  const float* b_pa  = (const float*)d_in[15];
  const float* W_po  = (const float*)d_in[16];
  const float* b_po  = (const float*)d_in[17];
  const float* W_paM = (const float*)d_in[18];
  const float* b_paM = (const float*)d_in[19];
  const float* W_poM = (const float*)d_in[20];
  const float* b_poM = (const float*)d_in[21];
  const float* gamma = (const float*)d_in[22];
  const float* beta  = (const float*)d_in[23];

  float* ws     = (float*)d_ws;
  float* X      = ws;            // 131072 floats
  float* master = ws + 131072;   // 256
  float* logits = ws + 131328;   // 2048
  float* out    = (float*)d_out;

  k1_build_x<<<512, 256, 0, stream>>>(x1, x2, W_t1, b_t1, W_t2, b_t2, X);
  k3_fused<<<dim3(64, 4), 1024, 0, stream>>>(X, W_att, b_att, w11, w22, w12,
                                             W_attM, b_attM, wM, W_pa, b_pa,
                                             W_po, b_po, gamma, beta,
                                             master, logits, out);
  k4_master_new<<<4, 256, 0, stream>>>(X, master, logits, W_paM, b_paM, W_poM, b_poM, out);
}

// Round 7
// 52.110 us; speedup vs baseline: 12.2579x; 1.0018x over previous
//
#include <hip/hip_runtime.h>

#define BB 4
#define NN 512
#define NH 256
#define DD 64

typedef __attribute__((ext_vector_type(8))) short bf16x8;
typedef __attribute__((ext_vector_type(16))) float f32x16;
union BF8 { bf16x8 v; unsigned int u[4]; };

__device__ __forceinline__ float wred_sum(float v) {
  v += __shfl_xor(v, 32);
  v += __shfl_xor(v, 16);
  v += __shfl_xor(v, 8);
  v += __shfl_xor(v, 4);
  v += __shfl_xor(v, 2);
  v += __shfl_xor(v, 1);
  return v;
}

__device__ __forceinline__ float wred_max(float v) {
  v = fmaxf(v, __shfl_xor(v, 32));
  v = fmaxf(v, __shfl_xor(v, 16));
  v = fmaxf(v, __shfl_xor(v, 8));
  v = fmaxf(v, __shfl_xor(v, 4));
  v = fmaxf(v, __shfl_xor(v, 2));
  v = fmaxf(v, __shfl_xor(v, 1));
  return v;
}

__device__ __forceinline__ unsigned int cvtpk_bf16(float lo, float hi) {
  unsigned int r;
  asm("v_cvt_pk_bf16_f32 %0, %1, %2" : "=v"(r) : "v"(lo), "v"(hi));
  return r;
}

// v_exp_f32 computes 2^x
__device__ __forceinline__ float fast_exp2(float x) {
  float r;
  asm("v_exp_f32 %0, %1" : "=v"(r) : "v"(x));
  return r;
}

// tanh(t) = 1 - 2/(exp(2t)+1)
__device__ __forceinline__ float fast_tanh(float t) {
  t = fminf(15.f, fmaxf(-15.f, t));
  float z = __expf(2.f * t);
  return 1.f - 2.f * __builtin_amdgcn_rcpf(z + 1.f);
}

// K1: x[b,n,:] = (n<256 ? x1@W_t1+b_t1 : x2@W_t2+b_t2)
__global__ __launch_bounds__(256)
void k1_build_x(const float* __restrict__ x1, const float* __restrict__ x2,
                const float* __restrict__ W_t1, const float* __restrict__ b_t1,
                const float* __restrict__ W_t2, const float* __restrict__ b_t2,
                float* __restrict__ X) {
  const int tid = threadIdx.x;
  const int lane = tid & 63;
  const int rq = tid >> 6;
  const int r = blockIdx.x * 4 + rq;   // 0..2047
  const int b = r >> 9;
  const int n = r & 511;
  const float* src; const float* W; const float* bias;
  if (n < NH) { src = x1 + (b * NH + n) * DD;        W = W_t1; bias = b_t1; }
  else        { src = x2 + (b * NH + (n - NH)) * DD; W = W_t2; bias = b_t2; }
  const float4* s4 = reinterpret_cast<const float4*>(src);
  float t0 = 0.f, t1 = 0.f, t2 = 0.f, t3 = 0.f;
#pragma unroll
  for (int c = 0; c < 16; ++c) {
    const float4 v = s4[c];
    t0 = fmaf(v.x, W[(4 * c + 0) * DD + lane], t0);
    t1 = fmaf(v.y, W[(4 * c + 1) * DD + lane], t1);
    t2 = fmaf(v.z, W[(4 * c + 2) * DD + lane], t2);
    t3 = fmaf(v.w, W[(4 * c + 3) * DD + lane], t3);
  }
  X[r * DD + lane] = ((t0 + t1) + (t2 + t3)) + bias[lane];
}

// K3: staging + master-mean + scores(MFMA) + softmax + agg + y(selu) + logits.
// 1024 threads = 16 waves = exactly 1 block/CU (LDS 151 KB).
// __launch_bounds__(1024, 4): 4 waves/EU -> 128-VGPR budget (R6's (1024,1) was
// degenerate -> compiler picked 64 VGPR -> scratch spills on the hot path).
__global__ __launch_bounds__(1024, 4)
void k3_fused(const float* __restrict__ X,
              const float* __restrict__ W_att, const float* __restrict__ b_att,
              const float* __restrict__ w11, const float* __restrict__ w22,
              const float* __restrict__ w12,
              const float* __restrict__ W_attM, const float* __restrict__ b_attM,
              const float* __restrict__ wM,
              const float* __restrict__ W_pa, const float* __restrict__ b_pa,
              const float* __restrict__ W_po, const float* __restrict__ b_po,
              const float* __restrict__ gamma, const float* __restrict__ beta,
              float* __restrict__ master, float* __restrict__ logits,
              float* __restrict__ out) {
  const int b = blockIdx.y;
  const int i0 = blockIdx.x * 8;
  const int tid = threadIdx.x;
  const int lane = tid & 63;
  const int w = tid >> 6;        // 0..15
  const int l31 = lane & 31;
  const int half = lane >> 5;
  const int j0 = w << 5;         // 32-wide j chunk

  __shared__ __align__(16) float Xlds[NN * DD];   // 128 KB
  __shared__ __align__(16) float sc[8 * NN];      // 16 KB
  __shared__ __align__(16) float red2[16][DD];    // 4 KB
  __shared__ __align__(16) float aggL[8][DD];     // 2 KB
  __shared__ __align__(16) float tblB[64];        // K2E*b_att in C-reg order
  __shared__ __align__(16) float tblW[2][64];     // -2*wsel in C-reg order, per jtype
  __shared__ __align__(16) float mastL[64];

  const float* __restrict__ Xb = X + b * NN * DD;
  const float K2E = 2.8853900817779268f;  // 2*log2(e)
  const int itype = (i0 >= NH);
  const int jtype = (w >= 8);

  // ---- stage X[b] -> LDS ----
  {
    const int c4 = (tid & 15) * 4;
    const int rh = tid >> 4;        // 0..63
#pragma unroll
    for (int it = 0; it < 8; ++it) {
      const int r = it * 64 + rh;
      *reinterpret_cast<float4*>(&Xlds[r * DD + c4]) =
          *reinterpret_cast<const float4*>(&Xb[r * DD + c4]);
    }
  }
  // coefficient tables in MFMA C-layout order: idx = ot*32 + hf*16 + r
  if (tid < 64) {
    const int ot = tid >> 5, hf = (tid >> 4) & 1, r = tid & 15;
    const int o = ot * 32 + (r & 3) + 8 * (r >> 2) + 4 * hf;
    tblB[tid] = K2E * b_att[o];
  } else if (tid >= 128 && tid < 256) {
    const int t = tid - 128;
    const int jt = t >> 6;
    const int idx = t & 63;
    const int ot = idx >> 5, hf = (idx >> 4) & 1, r = idx & 15;
    const int o = ot * 32 + (r & 3) + 8 * (r >> 2) + 4 * hf;
    const float* wsl = itype ? (jt ? w22 : w12) : (jt ? w12 : w11);
    tblW[jt][idx] = -2.f * wsl[o];
  }

  // ---- i-invariant register state ----
  // A-frags: W^T (unscaled bf16), row o = ot*32+l31, k-elem d = kt*16+half*8+e
  BF8 Wp[2][4];
#pragma unroll
  for (int ot = 0; ot < 2; ++ot)
#pragma unroll
    for (int kt = 0; kt < 4; ++kt) {
      const int o = ot * 32 + l31;
#pragma unroll
      for (int p = 0; p < 4; ++p) {
        const int d0 = kt * 16 + half * 8 + 2 * p;
        Wp[ot][kt].u[p] = cvtpk_bf16(W_att[d0 * DD + o], W_att[(d0 + 1) * DD + o]);
      }
    }

  // x_j packed bf16: col j = j0+l31, d = kt*16+half*8+e
  BF8 Xf[4];
#pragma unroll
  for (int kt = 0; kt < 4; ++kt) {
    const float* base = Xb + (j0 + l31) * DD + kt * 16 + half * 8;
    const float4 a = *reinterpret_cast<const float4*>(base);
    const float4 c = *reinterpret_cast<const float4*>(base + 4);
    Xf[kt].u[0] = cvtpk_bf16(a.x, a.y);
    Xf[kt].u[1] = cvtpk_bf16(a.z, a.w);
    Xf[kt].u[2] = cvtpk_bf16(c.x, c.y);
    Xf[kt].u[3] = cvtpk_bf16(c.z, c.w);
  }

  const float* wsel = itype ? (jtype ? w22 : w12) : (jtype ? w12 : w11);
  const float swv = wred_sum(wsel[lane]);   // sum_o wsel[o], wave-uniform

  __syncthreads();   // bar1: Xlds + tables ready

  // ---- master mean (fused k2): wave w sums rows [32w, 32w+32) ----
  {
    float s = 0.f;
    for (int r = w * 32; r < w * 32 + 32; ++r) s += Xlds[r * DD + lane];
    red2[w][lane] = s;
  }
  __syncthreads();   // bar2
  if (w == 0) {
    float s = 0.f;
#pragma unroll
    for (int k = 0; k < 16; ++k) s += red2[k][lane];
    s *= (1.f / 512.f);
    mastL[lane] = s;
    if (blockIdx.x == 0) master[b * DD + lane] = s;
  }

  // ---- phase 1: scores for 8 rows ----
#pragma unroll 1
  for (int ii = 0; ii < 8; ++ii) {
    // B-frags: bf16(x_i[d] * x_j[d])
    BF8 Bi[4];
#pragma unroll
    for (int kt = 0; kt < 4; ++kt) {
      const float4 xa = *reinterpret_cast<const float4*>(&Xlds[(i0 + ii) * DD + kt * 16 + half * 8]);
      const float4 xc = *reinterpret_cast<const float4*>(&Xlds[(i0 + ii) * DD + kt * 16 + half * 8 + 4]);
      unsigned int u;
      u = Xf[kt].u[0];
      Bi[kt].u[0] = cvtpk_bf16(xa.x * __uint_as_float(u << 16),
                               xa.y * __uint_as_float(u & 0xffff0000u));
      u = Xf[kt].u[1];
      Bi[kt].u[1] = cvtpk_bf16(xa.z * __uint_as_float(u << 16),
                               xa.w * __uint_as_float(u & 0xffff0000u));
      u = Xf[kt].u[2];
      Bi[kt].u[2] = cvtpk_bf16(xc.x * __uint_as_float(u << 16),
                               xc.y * __uint_as_float(u & 0xffff0000u));
      u = Xf[kt].u[3];
      Bi[kt].u[3] = cvtpk_bf16(xc.z * __uint_as_float(u << 16),
                               xc.w * __uint_as_float(u & 0xffff0000u));
    }
    float ptot = 0.f;
#pragma unroll
    for (int ot = 0; ot < 2; ++ot) {
      f32x16 C = {};
#pragma unroll
      for (int kt = 0; kt < 4; ++kt)
        C = __builtin_amdgcn_mfma_f32_32x32x16_bf16(Wp[ot][kt].v, Bi[kt].v, C, 0, 0, 0);
      const int base = ot * 32 + half * 16;
      float p = 0.f;
#pragma unroll
      for (int r = 0; r < 16; ++r) {
        // w*tanh(C+b): arg = K2E*(C+b); p += (-2w)*rcp(2^arg + 1); +sum_w later
        const float arg = fmaf(C[r], K2E, tblB[base + r]);
        const float e = fast_exp2(arg);
        p = fmaf(tblW[jtype][base + r], __builtin_amdgcn_rcpf(e + 1.f), p);
      }
      ptot += p;
    }
    ptot += __shfl_xor(ptot, 32);   // combine o-halves
    if (lane < 32) sc[ii * NN + j0 + l31] = swv + ptot;
  }
  __syncthreads();   // bar3: scores + mastL ready

  // ---- phase 2: 2 waves per row ----
  const int row = w & 7, part = w >> 3;
  const int irow = i0 + row;
  float v[8];
#pragma unroll
  for (int k = 0; k < 8; ++k) v[k] = sc[row * NN + lane + 64 * k];
  __syncthreads();   // bar3b: all score reads done before att overwrite
  float mx = fmaxf(fmaxf(fmaxf(v[0], v[1]), fmaxf(v[2], v[3])),
                   fmaxf(fmaxf(v[4], v[5]), fmaxf(v[6], v[7])));
  mx = wred_max(mx);
  float ssum = 0.f;
#pragma unroll
  for (int k = 0; k < 8; ++k) { v[k] = __expf(v[k] - mx); ssum += v[k]; }
  ssum = wred_sum(ssum);
  const float inv = __builtin_amdgcn_rcpf(ssum);
#pragma unroll
  for (int k = 0; k < 4; ++k) {
    const int kk = part * 4 + k;
    sc[row * NN + lane + 64 * kk] = v[kk] * inv;
  }

  // agg partial over own j-half
  float a0 = 0.f, a1 = 0.f, a2 = 0.f, a3 = 0.f;
  const float* scr = &sc[row * NN + part * 256];
  const int xof = part * 256 * DD;
  for (int jj = 0; jj < 64; ++jj) {
    const float4 at = *reinterpret_cast<const float4*>(&scr[jj * 4]);
    a0 = fmaf(at.x, Xlds[xof + (jj * 4 + 0) * DD + lane], a0);
    a1 = fmaf(at.y, Xlds[xof + (jj * 4 + 1) * DD + lane], a1);
    a2 = fmaf(at.z, Xlds[xof + (jj * 4 + 2) * DD + lane], a2);
    a3 = fmaf(at.w, Xlds[xof + (jj * 4 + 3) * DD + lane], a3);
  }
  red2[w][lane] = (a0 + a1) + (a2 + a3);
  __syncthreads();   // bar4

  if (part == 0) {
    // y = selu(BN(agg@W_pa + x@W_po + biases))
    const float aggv = red2[w][lane] + red2[w + 8][lane];
    aggL[row][lane] = aggv;
    float y = b_pa[lane] + b_po[lane];
#pragma unroll 8
    for (int d = 0; d < DD; ++d) {
      y = fmaf(aggL[row][d], W_pa[d * DD + lane], y);
      y = fmaf(Xlds[irow * DD + d], W_po[d * DD + lane], y);
    }
    const float RSQ = 0.9999950000374997f;   // 1/sqrt(1+1e-5)
    y = y * RSQ * gamma[lane] + beta[lane];
    const float SC_ = 1.0507009873554805f;
    const float AL = 1.6732632423543772f;
    y = (y > 0.f) ? (SC_ * y) : (SC_ * AL * (__expf(y) - 1.f));
    const int off = (irow < NH) ? ((b * NH + irow) * DD + lane)
                                : (BB * NH * DD + (b * NH + (irow - NH)) * DD + lane);
    out[off] = y;
  } else {
    // logits[b,irow] = wM . tanh((x_i*master)@W_attM + b_attM)
    float lg = b_attM[lane];
#pragma unroll 8
    for (int d = 0; d < DD; ++d)
      lg = fmaf(Xlds[irow * DD + d] * mastL[d], W_attM[d * DD + lane], lg);
    const float th = fast_tanh(lg);
    const float s = wred_sum(th * wM[lane]);
    if (lane == 0) logits[b * NN + irow] = s;
  }
}

// K4: softmax_n(logits) -> agg_m -> master_new (tail of out)
__global__ __launch_bounds__(256)
void k4_master_new(const float* __restrict__ X, const float* __restrict__ master,
                   const float* __restrict__ logits,
                   const float* __restrict__ W_paM, const float* __restrict__ b_paM,
                   const float* __restrict__ W_poM, const float* __restrict__ b_poM,
                   float* __restrict__ out) {
  const int b = blockIdx.x;
  const int tid = threadIdx.x;
  const int lane = tid & 63;
  const int q = tid >> 6;
  __shared__ float red[4][DD];
  __shared__ float r4[4];
  __shared__ float aggm_s[DD];
  __shared__ float mrow_s[DD];
  const float* lg = logits + b * NN;
  const float v0 = lg[tid];
  const float v1 = lg[tid + 256];
  float mx = wred_max(fmaxf(v0, v1));
  if (lane == 0) r4[q] = mx;
  __syncthreads();
  mx = fmaxf(fmaxf(r4[0], r4[1]), fmaxf(r4[2], r4[3]));
  float es = __expf(v0 - mx) + __expf(v1 - mx);
  es = wred_sum(es);
  __syncthreads();
  if (lane == 0) r4[q] = es;
  __syncthreads();
  const float S = r4[0] + r4[1] + r4[2] + r4[3];
  const float invS = 1.f / S;

  float acc = 0.f;
  for (int nn = q * 128; nn < q * 128 + 128; ++nn) {
    const float a = __expf(lg[nn] - mx);
    acc = fmaf(a, X[(b * NN + nn) * DD + lane], acc);
  }
  red[q][lane] = acc;
  __syncthreads();
  if (q == 0) {
    aggm_s[lane] =
        (red[0][lane] + red[1][lane] + red[2][lane] + red[3][lane]) * invS;
    mrow_s[lane] = master[b * DD + lane];
  }
  __syncthreads();
  float p = 0.f;
  for (int d = q * 16; d < q * 16 + 16; ++d) {
    p = fmaf(aggm_s[d], W_paM[d * DD + lane], p);
    p = fmaf(mrow_s[d], W_poM[d * DD + lane], p);
  }
  __syncthreads();
  red[q][lane] = p;
  __syncthreads();
  if (q == 0) {
    out[2 * BB * NH * DD + b * DD + lane] =
        red[0][lane] + red[1][lane] + red[2][lane] + red[3][lane] +
        b_paM[lane] + b_poM[lane];
  }
}

extern "C" void kernel_launch(void* const* d_in, const int* in_sizes, int n_in,
                              void* d_out, int out_size, void* d_ws, size_t ws_size,
                              hipStream_t stream) {
  const float* x1    = (const float*)d_in[0];
  const float* x2    = (const float*)d_in[1];
  const float* W_t1  = (const float*)d_in[2];
  const float* b_t1  = (const float*)d_in[3];
  const float* W_t2  = (const float*)d_in[4];
  const float* b_t2  = (const float*)d_in[5];
  const float* W_att = (const float*)d_in[6];
  const float* b_att = (const float*)d_in[7];
  const float* W_attM = (const float*)d_in[8];
  const float* b_attM = (const float*)d_in[9];
  const float* w11   = (const float*)d_in[10];
  const float* w22   = (const float*)d_in[11];
  const float* w12   = (const float*)d_in[12];
  const float* wM    = (const float*)d_in[13];
  const float* W_pa  = (const float*)d_in[14];
  const float* b_pa  = (const float*)d_in[15];
  const float* W_po  = (const float*)d_in[16];
  const float* b_po  = (const float*)d_in[17];
  const float* W_paM = (const float*)d_in[18];
  const float* b_paM = (const float*)d_in[19];
  const float* W_poM = (const float*)d_in[20];
  const float* b_poM = (const float*)d_in[21];
  const float* gamma = (const float*)d_in[22];
  const float* beta  = (const float*)d_in[23];

  float* ws     = (float*)d_ws;
  float* X      = ws;            // 131072 floats
  float* master = ws + 131072;   // 256
  float* logits = ws + 131328;   // 2048
  float* out    = (float*)d_out;

  k1_build_x<<<512, 256, 0, stream>>>(x1, x2, W_t1, b_t1, W_t2, b_t2, X);
  k3_fused<<<dim3(64, 4), 1024, 0, stream>>>(X, W_att, b_att, w11, w22, w12,
                                             W_attM, b_attM, wM, W_pa, b_pa,
                                             W_po, b_po, gamma, beta,
                                             master, logits, out);
  k4_master_new<<<4, 256, 0, stream>>>(X, master, logits, W_paM, b_paM, W_poM, b_poM, out);
}